// Round 7
// baseline (179.332 us; speedup 1.0000x reference)
//
#include <hip/hip_runtime.h>

typedef __attribute__((ext_vector_type(2))) float  f32x2;
typedef __attribute__((ext_vector_type(4))) float  f32x4;
typedef __attribute__((ext_vector_type(8))) __bf16 bf16x8;

__device__ __forceinline__ unsigned short f2bf(float f) {
    unsigned int u = __float_as_uint(f);
    u += 0x7FFFu + ((u >> 16) & 1u);   // RNE
    return (unsigned short)(u >> 16);
}

#define S_LEN 2048
#define E_DIM 512
#define NH 64
#define DK 8

// ---------------------------------------------------------------------------
// Kernel 1: quantum projection + per-token attention over heads (unchanged
// from R6). One wave per token, lane = head. Single-pass softmax, no max
// subtraction (|score| <= 2.83). LDS-pipe bound at ~24 cyc/g (2 ds_read_b128).
// ---------------------------------------------------------------------------
__global__ __launch_bounds__(256) void attn_stage(
    const float* __restrict__ X,    // (8,2048,512) fp32
    const float* __restrict__ TH,   // (8,) fp32
    unsigned short* __restrict__ A) // ws: 16384 x 512 bf16
{
    __shared__ __align__(16) float ldsP[4][NH][DK];   // 8 KB
    const int wv = threadIdx.x >> 6;
    const int h  = threadIdx.x & 63;
    const int t  = blockIdx.x * 4 + wv;     // token id
    const int b  = t >> 11;
    const int s  = t & (S_LEN - 1);

    const float4 t0 = *(const float4*)(TH);
    const float4 t1 = *(const float4*)(TH + 4);
    const float4 x0 = *(const float4*)(X + (size_t)t * E_DIM + h * DK);
    const float4 x1 = *(const float4*)(X + (size_t)t * E_DIM + h * DK + 4);

    float p[DK];
    p[0] = __cosf(x0.x + t0.x); p[1] = __cosf(x0.y + t0.y);
    p[2] = __cosf(x0.z + t0.z); p[3] = __cosf(x0.w + t0.w);
    p[4] = __cosf(x1.x + t1.x); p[5] = __cosf(x1.y + t1.y);
    p[6] = __cosf(x1.z + t1.z); p[7] = __cosf(x1.w + t1.w);

    {
        f32x4 p01 = {p[0], p[1], p[2], p[3]};
        f32x4 p23 = {p[4], p[5], p[6], p[7]};
        *(f32x4*)&ldsP[wv][h][0] = p01;
        *(f32x4*)&ldsP[wv][h][4] = p23;
    }
    __syncthreads();

    const float cfold = 0.35355339059327373f * 1.4426950408889634f;
    f32x2 ps[4];
    ps[0] = f32x2{p[0], p[1]} * cfold;
    ps[1] = f32x2{p[2], p[3]} * cfold;
    ps[2] = f32x2{p[4], p[5]} * cfold;
    ps[3] = f32x2{p[6], p[7]} * cfold;

    float sum = 0.f;
    f32x2 a2[4] = {f32x2{0.f,0.f}, f32x2{0.f,0.f}, f32x2{0.f,0.f}, f32x2{0.f,0.f}};
    #pragma unroll 8
    for (int g = 0; g < NH; ++g) {
        const f32x4 q0 = *(const f32x4*)&ldsP[wv][g][0];   // broadcast
        const f32x4 q1 = *(const f32x4*)&ldsP[wv][g][4];
        const f32x2 qa = __builtin_shufflevector(q0, q0, 0, 1);
        const f32x2 qb = __builtin_shufflevector(q0, q0, 2, 3);
        const f32x2 qc = __builtin_shufflevector(q1, q1, 0, 1);
        const f32x2 qd = __builtin_shufflevector(q1, q1, 2, 3);
        f32x2 d2 = ps[0] * qa;
        d2 += ps[1] * qb;
        d2 += ps[2] * qc;
        d2 += ps[3] * qd;
        const float e = __builtin_amdgcn_exp2f(d2.x + d2.y);
        sum += e;
        const f32x2 e2 = {e, e};
        a2[0] += e2 * qa; a2[1] += e2 * qb;
        a2[2] += e2 * qc; a2[3] += e2 * qd;
    }
    const float inv = __builtin_amdgcn_rcpf(sum);

    unsigned int ow[4];
    #pragma unroll
    for (int d = 0; d < 4; ++d)
        ow[d] = (unsigned int)f2bf(a2[d].x * inv) | ((unsigned int)f2bf(a2[d].y * inv) << 16);
    uint4 outv; outv.x = ow[0]; outv.y = ow[1]; outv.z = ow[2]; outv.w = ow[3];

    const int row = ((t >> 11) << 11) + h * 32 + ((t & (S_LEN-1)) >> 6);
    const int col = (t & 63) * DK;
    *(uint4*)(A + (size_t)row * E_DIM + col) = outv;
}

// ---------------------------------------------------------------------------
// Prepass: convert W (512x512 fp32) -> bf16 in ws.
// ---------------------------------------------------------------------------
__global__ __launch_bounds__(256) void convert_w(
    const float* __restrict__ W, unsigned short* __restrict__ Wb)
{
    const int i = blockIdx.x * 256 + threadIdx.x;     // 0..65535
    const float4 v = *(const float4*)(W + (size_t)i * 4);
    ushort4 o;
    o.x = f2bf(v.x); o.y = f2bf(v.y); o.z = f2bf(v.z); o.w = f2bf(v.w);
    *(ushort4*)(Wb + (size_t)i * 4) = o;
}

// ---------------------------------------------------------------------------
// Kernel 2: OUT = A @ W^T + bias.  M=16384, N=K=512.
// R7: 64x128 tile -> grid (256,4) = 1024 blocks = 4/CU (R6 was 2/CU,
// occupancy 16%, latency-exposed). Wave n-split: each wave 64x32 (4mi x 2ni).
// Epilogue via LDS transpose -> float4 stores, full 128B lines (R6 WRITE_SIZE
// was 110 MB vs 33.5 ideal from 64B half-line store granules).
// ---------------------------------------------------------------------------
#define BM 64
#define BN 128
#define BK 64

__global__ __launch_bounds__(256) void gemm_bias(
    const unsigned short* __restrict__ A,     // 16384 x 512 bf16 (ws)
    const unsigned short* __restrict__ W,     // 512 x 512 bf16 (ws)
    const float* __restrict__ BIAS,           // 512 fp32
    float* __restrict__ OUT)                  // 16384 x 512 fp32
{
    const int Kdim = 512;
    __shared__ __align__(16) unsigned short ldsA[BM * BK];  // 8 KB
    __shared__ __align__(16) unsigned short ldsB[BN * BK];  // 16 KB
    __shared__ __align__(16) float ldsT[16 * 132];          // 8.4 KB epilogue
    const int tid  = threadIdx.x;
    const int lane = tid & 63;
    const int wave = tid >> 6;
    const int quad = lane >> 4;
    const int l16  = lane & 15;
    const int m0 = blockIdx.x * BM;
    const int n0 = blockIdx.y * BN;
    const int wn = wave * 32;                 // wave's n-offset in tile

    f32x4 acc[4][2] = {};

    for (int kb = 0; kb < Kdim; kb += BK) {
        // A-tile 64x64: 512 chunks (2/thread); B-tile 128x64: 1024 (4/thread)
        uint4 av[2], wvv[4];
        int ar[2], as[2], br[4], bs[4];
        #pragma unroll
        for (int i = 0; i < 2; ++i) {
            const int c  = tid + i * 256;
            const int r  = c >> 3;
            const int cc = c & 7;
            ar[i] = r; as[i] = (cc ^ (r & 7)) * 8;
            av[i] = *(const uint4*)(A + (size_t)(m0 + r) * Kdim + kb + cc * 8);
        }
        #pragma unroll
        for (int i = 0; i < 4; ++i) {
            const int c  = tid + i * 256;
            const int r  = c >> 3;
            const int cc = c & 7;
            br[i] = r; bs[i] = (cc ^ (r & 7)) * 8;
            wvv[i] = *(const uint4*)(W + (size_t)(n0 + r) * Kdim + kb + cc * 8);
        }
        __syncthreads();   // previous iteration's readers done
        #pragma unroll
        for (int i = 0; i < 2; ++i) *(uint4*)(ldsA + ar[i] * BK + as[i]) = av[i];
        #pragma unroll
        for (int i = 0; i < 4; ++i) *(uint4*)(ldsB + br[i] * BK + bs[i]) = wvv[i];
        __syncthreads();   // staging visible

        #pragma unroll
        for (int ks = 0; ks < 2; ++ks) {
            bf16x8 bfr[2];
            #pragma unroll
            for (int ni = 0; ni < 2; ++ni) {
                const int rw = wn + ni*16 + l16;
                bfr[ni] = *(const bf16x8*)(ldsB + rw * BK + (((ks*4+quad) ^ (rw & 7)) * 8));
            }
            #pragma unroll
            for (int mi = 0; mi < 4; ++mi) {
                const int ra = mi*16 + l16;
                const bf16x8 afr = *(const bf16x8*)(ldsA + ra * BK + (((ks*4+quad) ^ (ra & 7)) * 8));
                #pragma unroll
                for (int ni = 0; ni < 2; ++ni)
                    acc[mi][ni] = __builtin_amdgcn_mfma_f32_16x16x32_bf16(
                        afr, bfr[ni], acc[mi][ni], 0, 0, 0);
            }
        }
    }

    // Epilogue: per 16-row group, transpose through LDS, store full lines.
    const int trow = tid >> 4;          // 0..15
    const int tcol = (tid & 15) * 8;    // 0..120
    const float4 bb0 = *(const float4*)(BIAS + n0 + tcol);
    const float4 bb1 = *(const float4*)(BIAS + n0 + tcol + 4);
    #pragma unroll
    for (int mi = 0; mi < 4; ++mi) {
        __syncthreads();   // previous pass reads (or K-loop) done
        #pragma unroll
        for (int ni = 0; ni < 2; ++ni) {
            const int col = wn + ni*16 + l16;
            #pragma unroll
            for (int r = 0; r < 4; ++r)
                ldsT[(quad*4 + r) * 132 + col] = acc[mi][ni][r];
        }
        __syncthreads();   // transpose visible
        float4 v0 = *(const float4*)&ldsT[trow * 132 + tcol];
        float4 v1 = *(const float4*)&ldsT[trow * 132 + tcol + 4];
        v0.x += bb0.x; v0.y += bb0.y; v0.z += bb0.z; v0.w += bb0.w;
        v1.x += bb1.x; v1.y += bb1.y; v1.z += bb1.z; v1.w += bb1.w;
        float* o = OUT + (size_t)(m0 + mi*16 + trow) * 512 + n0 + tcol;
        *(float4*)o = v0;
        *(float4*)(o + 4) = v1;
    }
}

extern "C" void kernel_launch(void* const* d_in, const int* in_sizes, int n_in,
                              void* d_out, int out_size, void* d_ws, size_t ws_size,
                              hipStream_t stream) {
    const float* X  = (const float*)d_in[0];   // x fp32
    const float* TH = (const float*)d_in[1];   // theta fp32
    const float* W  = (const float*)d_in[2];   // W_combine fp32
    const float* BI = (const float*)d_in[3];   // b_combine fp32
    float* OUT = (float*)d_out;                // fp32

    unsigned short* A  = (unsigned short*)d_ws;                        // 16 MiB
    unsigned short* Wb = (unsigned short*)((char*)d_ws + (16u << 20)); // 512 KiB

    attn_stage<<<dim3(4096), dim3(256), 0, stream>>>(X, TH, A);
    convert_w<<<dim3(256), dim3(256), 0, stream>>>(W, Wb);
    gemm_bias<<<dim3(256, 4), dim3(256), 0, stream>>>(A, Wb, BI, OUT);
}

// Round 9
// 133.140 us; speedup vs baseline: 1.3469x; 1.3469x over previous
//
#include <hip/hip_runtime.h>

typedef __attribute__((ext_vector_type(2))) float  f32x2;
typedef __attribute__((ext_vector_type(4))) float  f32x4;
typedef __attribute__((ext_vector_type(4))) unsigned int u32x4;
typedef __attribute__((ext_vector_type(8))) __bf16 bf16x8;

__device__ __forceinline__ unsigned short f2bf(float f) {
    unsigned int u = __float_as_uint(f);
    u += 0x7FFFu + ((u >> 16) & 1u);   // RNE
    return (unsigned short)(u >> 16);
}

#define S_LEN 2048
#define E_DIM 512
#define NH 64
#define DK 8

// ---------------------------------------------------------------------------
// Kernel 1: quantum projection + per-token attention over heads (unchanged
// from R6 — current best). One wave per token, lane = head.
// ---------------------------------------------------------------------------
__global__ __launch_bounds__(256) void attn_stage(
    const float* __restrict__ X,    // (8,2048,512) fp32
    const float* __restrict__ TH,   // (8,) fp32
    unsigned short* __restrict__ A) // ws: 16384 x 512 bf16
{
    __shared__ __align__(16) float ldsP[4][NH][DK];   // 8 KB
    const int wv = threadIdx.x >> 6;
    const int h  = threadIdx.x & 63;
    const int t  = blockIdx.x * 4 + wv;     // token id

    const float4 t0 = *(const float4*)(TH);
    const float4 t1 = *(const float4*)(TH + 4);
    const float4 x0 = *(const float4*)(X + (size_t)t * E_DIM + h * DK);
    const float4 x1 = *(const float4*)(X + (size_t)t * E_DIM + h * DK + 4);

    float p[DK];
    p[0] = __cosf(x0.x + t0.x); p[1] = __cosf(x0.y + t0.y);
    p[2] = __cosf(x0.z + t0.z); p[3] = __cosf(x0.w + t0.w);
    p[4] = __cosf(x1.x + t1.x); p[5] = __cosf(x1.y + t1.y);
    p[6] = __cosf(x1.z + t1.z); p[7] = __cosf(x1.w + t1.w);

    {
        f32x4 p01 = {p[0], p[1], p[2], p[3]};
        f32x4 p23 = {p[4], p[5], p[6], p[7]};
        *(f32x4*)&ldsP[wv][h][0] = p01;
        *(f32x4*)&ldsP[wv][h][4] = p23;
    }
    __syncthreads();

    const float cfold = 0.35355339059327373f * 1.4426950408889634f;
    f32x2 ps[4];
    ps[0] = f32x2{p[0], p[1]} * cfold;
    ps[1] = f32x2{p[2], p[3]} * cfold;
    ps[2] = f32x2{p[4], p[5]} * cfold;
    ps[3] = f32x2{p[6], p[7]} * cfold;

    float sum = 0.f;
    f32x2 a2[4] = {f32x2{0.f,0.f}, f32x2{0.f,0.f}, f32x2{0.f,0.f}, f32x2{0.f,0.f}};
    #pragma unroll 8
    for (int g = 0; g < NH; ++g) {
        const f32x4 q0 = *(const f32x4*)&ldsP[wv][g][0];   // broadcast
        const f32x4 q1 = *(const f32x4*)&ldsP[wv][g][4];
        const f32x2 qa = __builtin_shufflevector(q0, q0, 0, 1);
        const f32x2 qb = __builtin_shufflevector(q0, q0, 2, 3);
        const f32x2 qc = __builtin_shufflevector(q1, q1, 0, 1);
        const f32x2 qd = __builtin_shufflevector(q1, q1, 2, 3);
        f32x2 d2 = ps[0] * qa;
        d2 += ps[1] * qb;
        d2 += ps[2] * qc;
        d2 += ps[3] * qd;
        const float e = __builtin_amdgcn_exp2f(d2.x + d2.y);
        sum += e;
        const f32x2 e2 = {e, e};
        a2[0] += e2 * qa; a2[1] += e2 * qb;
        a2[2] += e2 * qc; a2[3] += e2 * qd;
    }
    const float inv = __builtin_amdgcn_rcpf(sum);

    unsigned int ow[4];
    #pragma unroll
    for (int d = 0; d < 4; ++d)
        ow[d] = (unsigned int)f2bf(a2[d].x * inv) | ((unsigned int)f2bf(a2[d].y * inv) << 16);
    uint4 outv; outv.x = ow[0]; outv.y = ow[1]; outv.z = ow[2]; outv.w = ow[3];

    const int row = ((t >> 11) << 11) + h * 32 + ((t & (S_LEN-1)) >> 6);
    const int col = (t & 63) * DK;
    *(uint4*)(A + (size_t)row * E_DIM + col) = outv;
}

// ---------------------------------------------------------------------------
// Prepass: convert W (512x512 fp32) -> bf16 in ws.
// ---------------------------------------------------------------------------
__global__ __launch_bounds__(256) void convert_w(
    const float* __restrict__ W, unsigned short* __restrict__ Wb)
{
    const int i = blockIdx.x * 256 + threadIdx.x;     // 0..65535
    const float4 v = *(const float4*)(W + (size_t)i * 4);
    ushort4 o;
    o.x = f2bf(v.x); o.y = f2bf(v.y); o.z = f2bf(v.z); o.w = f2bf(v.w);
    *(ushort4*)(Wb + (size_t)i * 4) = o;
}

// ---------------------------------------------------------------------------
// Kernel 2: OUT = A @ W^T + bias.  M=16384, N=K=512.
// R8 rationale: R6/R7 counters showed FETCH+WRITE == sum of per-block tile
// loads (132MB/195MB) — zero cross-block L2 reuse; A/OUT streams thrash the
// 4MB per-XCD L2. Fix the traffic FORMULA: BN=512 (full N) so every A byte
// is read by exactly ONE block, W (512KB) is the only L2-allocating stream
// (stays resident), and A loads / OUT stores are NONTEMPORAL (no L2
// pollution). BM=32 -> grid 512 = 2 blocks/CU.
// Expected traffic: A 16.8 + OUT 33.5 + W ~4 cold ≈ 55MB (was 195).
// R9: nontemporal builtins need ext_vector types, not HIP_vector_type.
// ---------------------------------------------------------------------------
#define GBM 32
#define GBK 32

__global__ __launch_bounds__(256) void gemm_bias(
    const unsigned short* __restrict__ A,     // 16384 x 512 bf16 (ws)
    const unsigned short* __restrict__ W,     // 512 x 512 bf16 (ws)
    const float* __restrict__ BIAS,           // 512 fp32
    float* __restrict__ OUT)                  // 16384 x 512 fp32
{
    __shared__ __align__(16) unsigned short ldsA[GBM * GBK];   // 2 KB
    __shared__ __align__(16) unsigned short ldsB[512 * GBK];   // 32 KB
    __shared__ __align__(16) float ldsT[4][16 * 132];          // 33.8 KB
    const int tid  = threadIdx.x;
    const int lane = tid & 63;
    const int wave = tid >> 6;
    const int quad = lane >> 4;
    const int l16  = lane & 15;
    const int m0 = blockIdx.x * GBM;
    const int wn = wave * 128;               // wave's global n-offset

    f32x4 acc[2][8] = {};

    for (int kb = 0; kb < 512; kb += GBK) {
        // W-tile 512x32: 2048 16B-chunks, 8/thread (normal loads -> L2 resident)
        u32x4 wv8[8];
        int wr[8], wsx[8];
        #pragma unroll
        for (int i = 0; i < 8; ++i) {
            const int c  = tid + i * 256;
            const int r  = c >> 2;            // W row 0..511
            const int cc = c & 3;             // chunk in row
            wr[i]  = r;
            wsx[i] = ((cc ^ (r & 3) ^ ((r >> 2) & 3))) * 8;
            wv8[i] = *(const u32x4*)(W + (size_t)r * 512 + kb + cc * 8);
        }
        // A-tile 32x32: 128 chunks, threads 0..127 (nontemporal: single-use)
        u32x4 aval; int arow = 0, asx = 0;
        if (tid < 128) {
            const int r  = tid >> 2;          // 0..31
            const int cc = tid & 3;
            arow = r;
            asx  = ((cc ^ (r & 3) ^ ((r >> 2) & 3))) * 8;
            aval = __builtin_nontemporal_load(
                       (const u32x4*)(A + (size_t)(m0 + r) * 512 + kb + cc * 8));
        }
        __syncthreads();   // previous iteration's readers done
        #pragma unroll
        for (int i = 0; i < 8; ++i)
            *(u32x4*)(ldsB + wr[i] * GBK + wsx[i]) = wv8[i];
        if (tid < 128)
            *(u32x4*)(ldsA + arow * GBK + asx) = aval;
        __syncthreads();   // staging visible

        bf16x8 bfr[8];
        #pragma unroll
        for (int ni = 0; ni < 8; ++ni) {
            const int rw = wn + ni * 16 + l16;
            const int sw = ((quad ^ (rw & 3) ^ ((rw >> 2) & 3))) * 8;
            bfr[ni] = *(const bf16x8*)(ldsB + rw * GBK + sw);
        }
        #pragma unroll
        for (int mi = 0; mi < 2; ++mi) {
            const int ra = mi * 16 + l16;
            const int sa = ((quad ^ (ra & 3) ^ ((ra >> 2) & 3))) * 8;
            const bf16x8 afr = *(const bf16x8*)(ldsA + ra * GBK + sa);
            #pragma unroll
            for (int ni = 0; ni < 8; ++ni)
                acc[mi][ni] = __builtin_amdgcn_mfma_f32_16x16x32_bf16(
                    afr, bfr[ni], acc[mi][ni], 0, 0, 0);
        }
    }

    // Epilogue: per-wave LDS transpose -> full-line nontemporal stores.
    const int c4 = lane & 31;                 // fixed col-group per lane
    float4 bias4 = *(const float4*)(BIAS + wn + c4 * 4);
    #pragma unroll
    for (int mi = 0; mi < 2; ++mi) {
        __syncthreads();   // prior pass reads (or K-loop LDS use) done
        #pragma unroll
        for (int ni = 0; ni < 8; ++ni) {
            #pragma unroll
            for (int r = 0; r < 4; ++r)
                ldsT[wave][(quad * 4 + r) * 132 + ni * 16 + l16] = acc[mi][ni][r];
        }
        __syncthreads();   // transpose visible
        #pragma unroll
        for (int j = 0; j < 8; ++j) {
            const int row = j * 2 + (lane >> 5);       // 0..15
            f32x4 v = *(const f32x4*)&ldsT[wave][row * 132 + c4 * 4];
            v.x += bias4.x; v.y += bias4.y; v.z += bias4.z; v.w += bias4.w;
            float* o = OUT + (size_t)(m0 + mi * 16 + row) * 512 + wn + c4 * 4;
            __builtin_nontemporal_store(v, (f32x4*)o);
        }
    }
}

extern "C" void kernel_launch(void* const* d_in, const int* in_sizes, int n_in,
                              void* d_out, int out_size, void* d_ws, size_t ws_size,
                              hipStream_t stream) {
    const float* X  = (const float*)d_in[0];   // x fp32
    const float* TH = (const float*)d_in[1];   // theta fp32
    const float* W  = (const float*)d_in[2];   // W_combine fp32
    const float* BI = (const float*)d_in[3];   // b_combine fp32
    float* OUT = (float*)d_out;                // fp32

    unsigned short* A  = (unsigned short*)d_ws;                        // 16 MiB
    unsigned short* Wb = (unsigned short*)((char*)d_ws + (16u << 20)); // 512 KiB

    attn_stage<<<dim3(4096), dim3(256), 0, stream>>>(X, TH, A);
    convert_w<<<dim3(256), dim3(256), 0, stream>>>(W, Wb);
    gemm_bias<<<dim3(512), dim3(256), 0, stream>>>(A, Wb, BI, OUT);
}